// Round 2
// baseline (14381.648 us; speedup 1.0000x reference)
//
#include <hip/hip_runtime.h>
#include <math.h>

#define B 64
#define P 196
#define ENCD 512
#define DECD 512
#define EMBD 256
#define ATTD 128
#define FFND 1024
#define VV 2000
#define MAXLEN 160
#define TSTEPS 159
#define EPS 1e-5f

// output chunk offsets (flat f32)
#define OUT_PRED ((size_t)0)
#define OUT_CAPS ((size_t)(B * TSTEPS * VV))
#define OUT_DECL (OUT_CAPS + (size_t)(B * MAXLEN))
#define OUT_ALPH (OUT_DECL + (size_t)B)
#define OUT_ORDR (OUT_ALPH + (size_t)(B * TSTEPS * P))

// GEMM decomposition: 32 column-slices (cg=g&31, same-slice blocks share an XCD)
//                   x  8 row-groups of 8 rows (rg=g>>5, r0=rg*8)
// Weight layouts are blocked [slice][kb][cols][4] so a wave's dwordx4 load is
// 1KB contiguous. Slice float sizes:
//   WA (P1: whh1|whh2|ln2g*fw1, 4096 cols, k=512): 128 cols/slice -> 65536 f
//   WB (P3: wih1|projw fused u=d*4+comp, 2048 cols, k=768): 64 cols -> 49152 f
//   WC (P4: ln1g*wih2 fused u=d*3+comp, 1536 cols, k=512): 48 cols -> 24576 f
//   WD (P2: fw2 padded to 2048 cols, k=1024): 64 cols -> 65536 f
//   Watt (att2|gate1, 256 cols, k-sliced 8x64): [ks][kb][256][4] -> 16384 f/ks

struct Ctx {
  const float* enc; const int* caps_in; const int* lens_in;
  const float* eaw; const float* eab; const float* daw; const float* dab;
  const float* faw; const float* fab;
  const float* gw1; const float* gb1; const float* gw2; const float* gb2;
  const float* emb;
  const float* wih1; const float* whh1; const float* bih1; const float* bhh1;
  const float* wih2; const float* whh2; const float* bih2; const float* bhh2;
  const float* projw; const float* projb;
  const float* ln1g; const float* ln1b; const float* ln2g; const float* ln2b;
  const float* fw1; const float* fb1; const float* fw2; const float* fb2;
  // ws
  int* leafs; int* root;
  int* order_i; int* declen; int* caps_s;
  float* EaT; float* att1;
  float* h1; float* h2; float* v1; float* v2;
  float* gin; float* fgr; float* gh1g; float* gh2g; float* att2acc;
  float* stats1; float* stats2;   // [2][64][2]
  float* WA; float* WB; float* WC; float* WD; float* Watt;
  float* Sf; float* cbf; float* Sg; float* cbg;
  float* out;
};

__device__ __forceinline__ float sigf(float x) { return 1.f / (1.f + __expf(-x)); }

// ---- device-coherent (MALL) helpers: relaxed agent atomics => sc1, no cache flushes
__device__ __forceinline__ float ld4(const float* p) {
  unsigned int u = __hip_atomic_load((const unsigned int*)p, __ATOMIC_RELAXED, __HIP_MEMORY_SCOPE_AGENT);
  return __uint_as_float(u);
}
__device__ __forceinline__ void st4(float* p, float v) {
  __hip_atomic_store((unsigned int*)p, __float_as_uint(v), __ATOMIC_RELAXED, __HIP_MEMORY_SCOPE_AGENT);
}
__device__ __forceinline__ void st8(float* p, float a, float b2) {
  unsigned long long v = ((unsigned long long)__float_as_uint(b2) << 32) | (unsigned long long)__float_as_uint(a);
  __hip_atomic_store((unsigned long long*)p, v, __ATOMIC_RELAXED, __HIP_MEMORY_SCOPE_AGENT);
}
__device__ __forceinline__ void atomF(float* p, float v) {
  __hip_atomic_fetch_add(p, v, __ATOMIC_RELAXED, __HIP_MEMORY_SCOPE_AGENT);
}
// 16B coherent load: issue many, then one vmwait()
__device__ __forceinline__ float4 ldg16(const float* p) {
  float4 d;
  asm volatile("global_load_dwordx4 %0, %1, off sc0 sc1" : "=v"(d) : "v"(p));
  return d;
}
__device__ __forceinline__ void vmwait() { asm volatile("s_waitcnt vmcnt(0)" ::: "memory"); }

// L2-warming prefetch (cached load, result sunk later without a wait)
__device__ __forceinline__ float pfl(const float* p) {
  float v;
  asm volatile("global_load_dword %0, %1, off" : "=v"(v) : "v"(p));
  return v;
}
__device__ __forceinline__ void pfsink8(float a, float b, float c2, float d,
                                        float e, float f, float g2, float h) {
  asm volatile("" :: "v"(a), "v"(b), "v"(c2), "v"(d), "v"(e), "v"(f), "v"(g2), "v"(h));
}
__device__ __forceinline__ void pfsink2(float a, float b) {
  asm volatile("" :: "v"(a), "v"(b));
}

__device__ __forceinline__ unsigned short tobf(float x) {
  unsigned int u = __float_as_uint(x);
  u += 0x7fffu + ((u >> 16) & 1u);
  return (unsigned short)(u >> 16);
}
__device__ __forceinline__ float frombf(unsigned short s) {
  return __uint_as_float(((unsigned int)s) << 16);
}

// ---------------- setup kernels ----------------

__global__ void k_order(Ctx c) {
  __shared__ int lens[B];
  int tid = threadIdx.x;
  lens[tid] = c.lens_in[tid];
  __syncthreads();
  int li = lens[tid];
  int pos = 0;
  for (int j = 0; j < B; ++j) {
    int lj = lens[j];
    pos += (lj > li || (lj == li && j < tid)) ? 1 : 0;
  }
  c.order_i[pos] = tid;
  c.declen[pos] = li - 1;
  c.out[OUT_ORDR + pos] = (float)tid;
  c.out[OUT_DECL + pos] = (float)(li - 1);
}

__global__ __launch_bounds__(256) void k_caps(Ctx c) {
  int idx = blockIdx.x * 256 + threadIdx.x;
  if (idx < B * MAXLEN) {
    int b = idx / MAXLEN, t = idx - b * MAXLEN;
    int v = c.caps_in[c.order_i[b] * MAXLEN + t];
    c.caps_s[idx] = v;
    c.out[OUT_CAPS + idx] = (float)v;
  }
}

__global__ __launch_bounds__(256) void k_eat(Ctx c) {
  int idx = blockIdx.x * 256 + threadIdx.x;
  if (idx < 128 * 512) {
    int k = idx >> 7, d = idx & 127;
    c.EaT[(size_t)k * 128 + d] = c.eaw[(size_t)d * 512 + k];
  }
}

__global__ __launch_bounds__(256) void k_att1(Ctx c) {
  __shared__ float Xs[8 * 512];
  int tid = threadIdx.x;
  int r0 = blockIdx.x * 8;
  for (int idx = tid; idx < 8 * 512; idx += 256) {
    int rr = idx >> 9, k = idx & 511;
    int r = r0 + rr;
    int b = r / P, p = r - b * P;
    int ob = c.order_i[b];
    Xs[idx] = c.enc[((size_t)(ob * P + p)) * ENCD + k];
  }
  __syncthreads();
  int d = tid >> 1, kh = tid & 1;
  float acc[8];
#pragma unroll
  for (int rr = 0; rr < 8; ++rr) acc[rr] = 0.f;
  int kbase = kh * 256;
  for (int k = 0; k < 256; ++k) {
    float w = c.EaT[(size_t)(kbase + k) * 128 + d];
#pragma unroll
    for (int rr = 0; rr < 8; ++rr) acc[rr] = fmaf(w, Xs[rr * 512 + kbase + k], acc[rr]);
  }
#pragma unroll
  for (int rr = 0; rr < 8; ++rr) {
    acc[rr] += __shfl_xor(acc[rr], 1);
    if (kh == 0) c.att1[(size_t)(r0 + rr) * 128 + d] = acc[rr];
  }
}

__global__ __launch_bounds__(256) void k_wpa(Ctx c) {
  int s = blockIdx.x;
  float* dst = c.WA + (size_t)s * 65536;
  for (int idx = threadIdx.x; idx < 65536; idx += 256) {
    int kb = idx >> 9, r = idx & 511, cc = r >> 2, jj = r & 3;
    int col = s * 128 + cc, k = kb * 4 + jj;
    float v;
    if (col < 1536) v = c.whh1[(size_t)col * 512 + k];
    else if (col < 3072) v = c.whh2[(size_t)(col - 1536) * 512 + k];
    else v = c.ln2g[k] * c.fw1[(size_t)(col - 3072) * 512 + k];
    dst[idx] = v;
  }
}

__global__ __launch_bounds__(256) void k_wpb(Ctx c) {
  int s = blockIdx.x;
  float* dst = c.WB + (size_t)s * 49152;
  for (int idx = threadIdx.x; idx < 49152; idx += 256) {
    int kb = idx >> 8, r = idx & 255, cc = r >> 2, jj = r & 3;
    int u = s * 64 + cc, k = kb * 4 + jj;
    int d = u >> 2, comp = u & 3;
    dst[idx] = (comp < 3) ? c.wih1[(size_t)(comp * 512 + d) * 768 + k]
                          : c.projw[(size_t)d * 768 + k];
  }
}

__global__ __launch_bounds__(256) void k_wpc(Ctx c) {
  int s = blockIdx.x;
  float* dst = c.WC + (size_t)s * 24576;
  for (int idx = threadIdx.x; idx < 24576; idx += 256) {
    int kb = idx / 192, r = idx - kb * 192, cc = r >> 2, jj = r & 3;
    int u = s * 48 + cc, k = kb * 4 + jj;
    int d = u / 3, comp = u - d * 3;
    dst[idx] = c.ln1g[k] * c.wih2[(size_t)(comp * 512 + d) * 512 + k];
  }
}

__global__ __launch_bounds__(256) void k_wpd(Ctx c) {
  int s = blockIdx.x;
  float* dst = c.WD + (size_t)s * 65536;
  for (int idx = threadIdx.x; idx < 65536; idx += 256) {
    int kb = idx >> 8, r = idx & 255, cc = r >> 2, jj = r & 3;
    int vcol = s * 64 + cc, k = kb * 4 + jj;
    dst[idx] = (vcol < 2000) ? c.fw2[(size_t)vcol * 1024 + k] : 0.f;
  }
}

__global__ __launch_bounds__(256) void k_watt(Ctx c) {
  int ks = blockIdx.x;
  float* dst = c.Watt + (size_t)ks * 16384;
  for (int idx = threadIdx.x; idx < 16384; idx += 256) {
    int kb = idx >> 10, r = idx & 1023, cc = r >> 2, jj = r & 3;
    int k = ks * 64 + kb * 4 + jj;
    dst[idx] = (cc < 128) ? c.daw[(size_t)cc * 512 + k] : c.gw1[(size_t)(cc - 128) * 512 + k];
  }
}

__global__ __launch_bounds__(256) void k_consts(Ctx c) {
  __shared__ float r1[256], r2[256];
  int i = blockIdx.x, tid = threadIdx.x;
  float a = 0.f, b2 = 0.f;
  if (i < 1024) {
    const float* w = c.fw1 + (size_t)i * 512;
    for (int k = tid; k < 512; k += 256) { a = fmaf(c.ln2g[k], w[k], a); b2 = fmaf(c.ln2b[k], w[k], b2); }
  } else {
    const float* w = c.wih2 + (size_t)(i - 1024) * 512;
    for (int k = tid; k < 512; k += 256) { a = fmaf(c.ln1g[k], w[k], a); b2 = fmaf(c.ln1b[k], w[k], b2); }
  }
  r1[tid] = a; r2[tid] = b2;
  __syncthreads();
  for (int s = 128; s > 0; s >>= 1) {
    if (tid < s) { r1[tid] += r1[tid + s]; r2[tid] += r2[tid + s]; }
    __syncthreads();
  }
  if (tid == 0) {
    if (i < 1024) { c.Sf[i] = r1[0]; c.cbf[i] = r2[0] + c.fb1[i]; }
    else { c.Sg[i - 1024] = r1[0]; c.cbg[i - 1024] = r2[0] + c.bih2[i - 1024]; }
  }
}

// ---------------- persistent kernel ----------------

__device__ __forceinline__ void gridbar(int* leafs, int* root, int ph) {
  __builtin_amdgcn_s_waitcnt(0);   // drain this wave's sc1 stores (acked at MALL)
  __syncthreads();
  if (threadIdx.x == 0) {
    int old = __hip_atomic_fetch_add(&leafs[(blockIdx.x & 7) * 32], 1,
                                     __ATOMIC_RELAXED, __HIP_MEMORY_SCOPE_AGENT);
    if (old == ph * 32 - 1)
      __hip_atomic_fetch_add(root, 1, __ATOMIC_RELAXED, __HIP_MEMORY_SCOPE_AGENT);
    while (__hip_atomic_load(root, __ATOMIC_RELAXED, __HIP_MEMORY_SCOPE_AGENT) < ph * 8)
      __builtin_amdgcn_s_sleep(1);
  }
  __syncthreads();
}

__global__ __launch_bounds__(512) void persist(Ctx c) {
  __shared__ unsigned short att1L[196 * 130];  // bf16, row-padded (+2)
  __shared__ unsigned short encL[196 * 128];   // bf16
  __shared__ float SH[12288];                  // XS | RED union (per-phase split)
  __shared__ float eL[256];
  __shared__ float alphaL[256];
  __shared__ float att2sL[128], fawL[128], dabL[128], gb1L[128], gw2L[128];
  __shared__ float wred[16];
  __shared__ float sstat[16];
  __shared__ int declenI[64];
  __shared__ float gb2v, fabv;

  const int g = blockIdx.x;
  const int tid = threadIdx.x;
  const int cg = g & 31;         // column slice (same-slice blocks share an XCD)
  const int rg = g >> 5;         // 8 row-groups of 8 rows
  const int r0 = rg * 8;
  const int bA = g >> 2, q = g & 3;  // attention mapping
  const int kc = tid >> 6;       // wave index = k-chunk (wave-uniform x broadcast)
  const int ct = tid & 63;       // lane = column(s)

  // ---- one-time staging ----
  if (tid < 128) {
    fawL[tid] = c.faw[tid];
    dabL[tid] = c.dab[tid] + c.eab[tid];
    gb1L[tid] = c.gb1[tid];
    gw2L[tid] = c.gw2[tid];
  }
  if (tid == 0) { gb2v = c.gb2[0]; fabv = c.fab[0]; }
  if (tid < 64) declenI[tid] = c.declen[tid];
  {
    const int ob = c.order_i[bA];
    for (int idx = tid; idx < 196 * 128; idx += 512) {
      int p = idx >> 7, j = idx & 127;
      att1L[p * 130 + j] = tobf(c.att1[((size_t)bA * P + p) * 128 + j]);
      encL[idx] = tobf(c.enc[((size_t)(ob * P + p)) * 512 + q * 128 + j]);
    }
  }
  __syncthreads();

  int ph = 0;
  for (int t = 0; t < MAXLEN; ++t) {
    // ===== PHASE1: gh1 | gh2 | fg(LN2-folded,relu) + att2/gate k-split ========
    {
      float* XS = SH;            // 4096 f (8 rows x 512, this slice's region)
      float* RED = SH + 4096;    // 8192 f (8kc x 8row x 128col)
      const float* hsrc = ((cg < 12) ? c.h1 : (cg < 24) ? c.h2 : c.v2) + (size_t)r0 * 512;
      float4 s0 = ldg16(hsrc + tid * 4);
      float4 s1 = ldg16(hsrc + 2048 + tid * 4);
      if (tid < 8) {
        int slot = (t + 1) & 1;
        float a = ld4(c.stats2 + slot * 128 + (r0 + tid) * 2);
        float b2 = ld4(c.stats2 + slot * 128 + (r0 + tid) * 2 + 1);
        float m = a * (1.f / 512.f);
        float va = b2 * (1.f / 512.f) - m * m;
        sstat[tid] = m; sstat[8 + tid] = rsqrtf(va + EPS);
      }
      vmwait();
      *(float4*)(XS + tid * 4) = s0;
      *(float4*)(XS + 2048 + tid * 4) = s1;
      __syncthreads();

      {
        const float* wp = c.WA + (size_t)cg * 65536 + kc * 8192 + ct * 4;
        const float* xb = XS + kc * 64;
        float acc[8][2];
#pragma unroll
        for (int r = 0; r < 8; ++r) { acc[r][0] = 0.f; acc[r][1] = 0.f; }
#pragma unroll 4
        for (int i = 0; i < 16; ++i) {
          float4 w0 = *(const float4*)(wp + i * 512);
          float4 w1 = *(const float4*)(wp + i * 512 + 256);
#pragma unroll
          for (int r = 0; r < 8; ++r) {
            float4 x = *(const float4*)(xb + r * 512 + i * 4);
            acc[r][0] = fmaf(w0.x, x.x, fmaf(w0.y, x.y, fmaf(w0.z, x.z, fmaf(w0.w, x.w, acc[r][0]))));
            acc[r][1] = fmaf(w1.x, x.x, fmaf(w1.y, x.y, fmaf(w1.z, x.z, fmaf(w1.w, x.w, acc[r][1]))));
          }
        }
#pragma unroll
        for (int r = 0; r < 8; ++r) {
          RED[(kc * 8 + r) * 128 + ct] = acc[r][0];
          RED[(kc * 8 + r) * 128 + ct + 64] = acc[r][1];
        }
      }
      // att2 (daw) + gate1 (gw1): k-sliced across the 8 h2-region slices 16..23,
      // accumulated into att2acc via device-scope atomics (zeroed each P3).
      if (cg >= 16 && cg < 24) {
        const int ks_att = cg - 16;
        const int ct2 = tid >> 1, half = tid & 1;
        const float* wp = c.Watt + (size_t)ks_att * 16384 + half * 8192 + ct2 * 4;
        const float* xb = XS + ks_att * 64 + half * 32;
        float a[8];
#pragma unroll
        for (int r = 0; r < 8; ++r) a[r] = 0.f;
#pragma unroll
        for (int i = 0; i < 8; ++i) {
          float4 w = *(const float4*)(wp + i * 1024);
#pragma unroll
          for (int r = 0; r < 8; ++r) {
            float4 x = *(const float4*)(xb + r * 512 + i * 4);
            a[r] = fmaf(w.x, x.x, fmaf(w.y, x.y, fmaf(w.z, x.z, fmaf(w.w, x.w, a[r]))));
          }
        }
#pragma unroll
        for (int r = 0; r < 8; ++r) {
          a[r] += __shfl_xor(a[r], 1);
          if (half == 0) atomF(c.att2acc + (r0 + r) * 256 + ct2, a[r]);
        }
      }
      // prefetch next phase's weight slice (WD) into L2
      float pw[8];
      {
        const float* pb = c.WD + (size_t)cg * 65536 + tid * 16;
#pragma unroll
        for (int i = 0; i < 8; ++i) pw[i] = pfl(pb + i * 8192);
      }
      __syncthreads();
      {
        int row = tid >> 6, cp = (tid & 63) * 2;
        float s0_ = 0.f, s1_ = 0.f;
#pragma unroll
        for (int k8 = 0; k8 < 8; ++k8) {
          float2 v = *(const float2*)(RED + (k8 * 8 + row) * 128 + cp);
          s0_ += v.x; s1_ += v.y;
        }
        int bb = r0 + row;
        int gcol = cg * 128 + cp;
        if (cg < 12) st8(c.gh1g + bb * 1536 + gcol, s0_, s1_);
        else if (cg < 24) st8(c.gh2g + bb * 1536 + (gcol - 1536), s0_, s1_);
        else {
          int cf = gcol - 3072;
          float m2 = sstat[row], i2 = sstat[8 + row];
          float v0 = i2 * (s0_ - m2 * c.Sf[cf]) + c.cbf[cf];
          float v1v = i2 * (s1_ - m2 * c.Sf[cf + 1]) + c.cbf[cf + 1];
          st8(c.fgr + bb * 1024 + cf, fmaxf(v0, 0.f), fmaxf(v1v, 0.f));
        }
      }
      pfsink8(pw[0], pw[1], pw[2], pw[3], pw[4], pw[5], pw[6], pw[7]);
    }
    gridbar(c.leafs, c.root, ++ph);

    // ===== PHASE2: preds GEMM (store t-1) + stats zero + full attention + gin ===
    {
      float* XS = SH;            // 8192 f (8 rows x 1024 fgr)
      float* RED = SH + 8192;    // 4096 f
      const float* fsrc = c.fgr + (size_t)r0 * 1024;
      float4 s0 = ldg16(fsrc + tid * 4);
      float4 s1 = ldg16(fsrc + 2048 + tid * 4);
      float4 s2 = ldg16(fsrc + 4096 + tid * 4);
      float4 s3 = ldg16(fsrc + 6144 + tid * 4);
      float a2r = 0.f, g1r = 0.f;
      if (tid < 128) {
        a2r = ld4(c.att2acc + bA * 256 + tid);
        g1r = ld4(c.att2acc + bA * 256 + 128 + tid);
      }
      if (g == 0) {
        int sl = t & 1;
        if (tid < 128) st4(c.stats1 + sl * 128 + tid, 0.f);
        else if (tid < 256) st4(c.stats2 + sl * 128 + (tid - 128), 0.f);
      }
      vmwait();
      *(float4*)(XS + tid * 4) = s0;
      *(float4*)(XS + 2048 + tid * 4) = s1;
      *(float4*)(XS + 4096 + tid * 4) = s2;
      *(float4*)(XS + 6144 + tid * 4) = s3;
      if (tid < 128) {
        att2sL[tid] = a2r + dabL[tid];
        float g1 = fmaxf(g1r + gb1L[tid], 0.f);
        float gv = g1 * gw2L[tid];
#pragma unroll
        for (int w = 1; w < 64; w <<= 1) gv += __shfl_xor(gv, w);
        if ((tid & 63) == 0) wred[tid >> 6] = gv;
      }
      __syncthreads();   // S1: XS + att2sL + wred[0..1]

      {
        const float* wp = c.WD + (size_t)cg * 65536 + kc * 8192 + ct * 4;
        const float* xb = XS + kc * 128;
        float acc[8];
#pragma unroll
        for (int r = 0; r < 8; ++r) acc[r] = 0.f;
#pragma unroll 4
        for (int i = 0; i < 32; ++i) {
          float4 w = *(const float4*)(wp + i * 256);
#pragma unroll
          for (int r = 0; r < 8; ++r) {
            float4 x = *(const float4*)(xb + r * 1024 + i * 4);
            acc[r] = fmaf(w.x, x.x, fmaf(w.y, x.y, fmaf(w.z, x.z, fmaf(w.w, x.w, acc[r]))));
          }
        }
#pragma unroll
        for (int r = 0; r < 8; ++r) RED[(kc * 8 + r) * 64 + ct] = acc[r];
      }
      // prefetch next phase's weight slice (WB)
      float pw[6];
      {
        const float* pb = c.WB + (size_t)cg * 49152 + tid * 16;
#pragma unroll
        for (int i = 0; i < 6; ++i) pw[i] = pfl(pb + i * 8192);
      }
      __syncthreads();   // S2: RED ready
      {
        int row = tid >> 6, cl = tid & 63;
        float s = 0.f;
#pragma unroll
        for (int k8 = 0; k8 < 8; ++k8) s += RED[(k8 * 8 + row) * 64 + cl];
        int bb = r0 + row, vcol = cg * 64 + cl;
        if (vcol < 2000 && t > 0 && (t - 1) < declenI[bb])
          c.out[OUT_PRED + ((size_t)bb * TSTEPS + (t - 1)) * VV + vcol] = s + c.fb2[vcol];
      }
      // ---- attention (per b=bA, redundant across the 4 q-blocks) ----
      {
        int p = tid >> 1, jh = tid & 1;
        float e = 0.f;
        if (p < 196) {
          const unsigned short* ap = att1L + p * 130 + jh * 64;
#pragma unroll 8
          for (int j = 0; j < 64; ++j)
            e = fmaf(fmaxf(frombf(ap[j]) + att2sL[jh * 64 + j], 0.f), fawL[jh * 64 + j], e);
        }
        e += __shfl_xor(e, 1);
        if (jh == 0 && p < 196) eL[p] = e + fabv;
      }
      __syncthreads();   // S3: eL ready (also RED reads done before awe reuse)
      float ev = (tid < 196) ? eL[tid] : -3.0e38f;
      if (tid < 256) {
        float mv = ev;
#pragma unroll
        for (int w = 1; w < 64; w <<= 1) mv = fmaxf(mv, __shfl_xor(mv, w));
        if ((tid & 63) == 0) wred[2 + (tid >> 6)] = mv;
      }
      __syncthreads();   // S4
      float mx = fmaxf(fmaxf(wred[2], wred[3]), fmaxf(wred[4], wred[5]));
      float ex = (tid < 196) ? __expf(ev - mx) : 0.f;
      if (tid < 256) {
        float sv = ex;
#pragma unroll
        for (int w = 1; w < 64; w <<= 1) sv += __shfl_xor(sv, w);
        if ((tid & 63) == 0) wred[6 + (tid >> 6)] = sv;
      }
      __syncthreads();   // S5
      float inv = 1.f / (wred[6] + wred[7] + wred[8] + wred[9]);
      float gate = sigf(wred[0] + wred[1] + gb2v);
      if (tid < 256) alphaL[tid] = ex * inv;
      if (q == 0 && tid < 196 && t < declenI[bA])
        c.out[OUT_ALPH + ((size_t)bA * TSTEPS + t) * P + tid] = ex * inv;
      __syncthreads();   // S6: alphaL ready
      {
        int el = tid & 127, pq = tid >> 7;
        const unsigned short* ep2 = encL + (size_t)(pq * 49) * 128 + el;
        const float* alp = alphaL + pq * 49;
        float s_ = 0.f;
#pragma unroll
        for (int i = 0; i < 49; ++i) s_ = fmaf(alp[i], frombf(ep2[(size_t)i * 128]), s_);
        RED[tid] = s_;
      }
      __syncthreads();   // S7
      if (tid < 128) {
        float aw = RED[tid] + RED[128 + tid] + RED[256 + tid] + RED[384 + tid];
        st4(c.gin + bA * 768 + 256 + q * 128 + tid, aw * gate);
      }
      if (q == 1 && tid < 256) {
        int tok = c.caps_s[bA * MAXLEN + t];
        st4(c.gin + bA * 768 + tid, c.emb[(size_t)tok * 256 + tid]);
      }
      pfsink8(pw[0], pw[1], pw[2], pw[3], pw[4], pw[5], pw[0], pw[1]);
    }
    gridbar(c.leafs, c.root, ++ph);

    // ===== PHASE3: gin GEMM + GRU1 + v1 + stats1 (+ att2acc zero) ==============
    {
      float* XS = SH;            // 6144 f (8 rows x 768 gin)
      float* RED = SH + 6144;    // 4096 f
      const float* gsrc = c.gin + (size_t)r0 * 768;
      float4 s0 = ldg16(gsrc + tid * 4);
      float4 s1 = ldg16(gsrc + 2048 + tid * 4);
      float4 s2 = ldg16(gsrc + 4096 + tid * 4);
      if (g < 32) st4(c.att2acc + g * 512 + tid, 0.f);
      vmwait();
      *(float4*)(XS + tid * 4) = s0;
      *(float4*)(XS + 2048 + tid * 4) = s1;
      *(float4*)(XS + 4096 + tid * 4) = s2;
      __syncthreads();

      {
        const float* wp = c.WB + (size_t)cg * 49152 + kc * 6144 + ct * 4;
        const float* xb = XS + kc * 96;
        float acc[8];
#pragma unroll
        for (int r = 0; r < 8; ++r) acc[r] = 0.f;
#pragma unroll 4
        for (int i = 0; i < 24; ++i) {
          float4 w = *(const float4*)(wp + i * 256);
#pragma unroll
          for (int r = 0; r < 8; ++r) {
            float4 x = *(const float4*)(xb + r * 768 + i * 4);
            acc[r] = fmaf(w.x, x.x, fmaf(w.y, x.y, fmaf(w.z, x.z, fmaf(w.w, x.w, acc[r]))));
          }
        }
#pragma unroll
        for (int r = 0; r < 8; ++r) RED[(kc * 8 + r) * 64 + ct] = acc[r];
      }
      // prefetch next phase's weight slice (WC)
      float pw[3];
      {
        const float* pb = c.WC + (size_t)cg * 24576 + tid * 16;
#pragma unroll
        for (int i = 0; i < 3; ++i) pw[i] = pfl(pb + i * 8192);
      }
      __syncthreads();
      if (tid < 128) {
        int row = tid >> 4, dl = tid & 15;
        int bb = r0 + row, d = cg * 16 + dl;
        float gi0 = 0.f, gi1 = 0.f, gi2v = 0.f, gi3 = 0.f;
#pragma unroll
        for (int k8 = 0; k8 < 8; ++k8) {
          float4 v = *(const float4*)(RED + (k8 * 8 + row) * 64 + dl * 4);
          gi0 += v.x; gi1 += v.y; gi2v += v.z; gi3 += v.w;
        }
        float gir = gi0 + c.bih1[d];
        float giz = gi1 + c.bih1[512 + d];
        float gig = gi2v + c.bih1[1024 + d];
        float pj = gi3 + c.projb[d];
        float hr = ld4(c.gh1g + bb * 1536 + d) + c.bhh1[d];
        float hz = ld4(c.gh1g + bb * 1536 + 512 + d) + c.bhh1[512 + d];
        float hg = ld4(c.gh1g + bb * 1536 + 1024 + d) + c.bhh1[1024 + d];
        float r_ = sigf(gir + hr);
        float z_ = sigf(giz + hz);
        float n_ = tanhf(gig + r_ * hg);
        float hold = ld4(c.h1 + bb * 512 + d);
        float hnew = (1.f - z_) * n_ + z_ * hold;
        st4(c.h1 + bb * 512 + d, (t < declenI[bb]) ? hnew : hold);
        float v1v = hnew + pj;
        st4(c.v1 + bb * 512 + d, v1v);
        float ss = v1v, sq = v1v * v1v;
#pragma unroll
        for (int w = 1; w < 16; w <<= 1) { ss += __shfl_xor(ss, w); sq += __shfl_xor(sq, w); }
        if (dl == 0) {
          atomF(c.stats1 + (t & 1) * 128 + bb * 2, ss);
          atomF(c.stats1 + (t & 1) * 128 + bb * 2 + 1, sq);
        }
      }
      pfsink8(pw[0], pw[1], pw[2], pw[0], pw[1], pw[2], pw[0], pw[1]);
    }
    gridbar(c.leafs, c.root, ++ph);

    // ===== PHASE4: gi2 GEMM (LN1-folded) + GRU2 + v2 + stats2 ==================
    {
      float* XS = SH;            // 4096 f (8 rows x 512 v1)
      float* RED = SH + 4096;    // 3072 f
      const float* vsrc = c.v1 + (size_t)r0 * 512;
      float4 s0 = ldg16(vsrc + tid * 4);
      float4 s1 = ldg16(vsrc + 2048 + tid * 4);
      if (tid < 8) {
        float a = ld4(c.stats1 + (t & 1) * 128 + (r0 + tid) * 2);
        float b2 = ld4(c.stats1 + (t & 1) * 128 + (r0 + tid) * 2 + 1);
        float m = a * (1.f / 512.f);
        float va = b2 * (1.f / 512.f) - m * m;
        sstat[tid] = m; sstat[8 + tid] = rsqrtf(va + EPS);
      }
      vmwait();
      *(float4*)(XS + tid * 4) = s0;
      *(float4*)(XS + 2048 + tid * 4) = s1;
      __syncthreads();

      if (ct < 48) {
        const float* wp = c.WC + (size_t)cg * 24576 + kc * 3072 + ct * 4;
        const float* xb = XS + kc * 64;
        float acc[8];
#pragma unroll
        for (int r = 0; r < 8; ++r) acc[r] = 0.f;
#pragma unroll 4
        for (int i = 0; i < 16; ++i) {
          float4 w = *(const float4*)(wp + i * 192);
#pragma unroll
          for (int r = 0; r < 8; ++r) {
            float4 x = *(const float4*)(xb + r * 512 + i * 4);
            acc[r] = fmaf(w.x, x.x, fmaf(w.y, x.y, fmaf(w.z, x.z, fmaf(w.w, x.w, acc[r]))));
          }
        }
#pragma unroll
        for (int r = 0; r < 8; ++r) RED[(kc * 8 + r) * 48 + ct] = acc[r];
      }
      // prefetch next step's P1 weight slice (WA) (+ Watt for the att blocks)
      float pw[8];
      {
        const float* pb = c.WA + (size_t)cg * 65536 + tid * 16;
#pragma unroll
        for (int i = 0; i < 8; ++i) pw[i] = pfl(pb + i * 8192);
      }
      float pa0 = 0.f, pa1 = 0.f;
      if (cg >= 16 && cg < 24) {
        const float* pb = c.Watt + (size_t)(cg - 16) * 16384 + tid * 16;
        pa0 = pfl(pb);
        pa1 = pfl(pb + 8192);
      }
      __syncthreads();
      if (tid < 128) {
        int row = tid >> 4, dl = tid & 15;
        int bb = r0 + row, d = cg * 16 + dl;
        float gi0 = 0.f, gi1 = 0.f, gi2v = 0.f;
#pragma unroll
        for (int k8 = 0; k8 < 8; ++k8) {
          const float* rp = RED + (k8 * 8 + row) * 48 + dl * 3;
          gi0 += rp[0]; gi1 += rp[1]; gi2v += rp[2];
        }
        float m1 = sstat[row], i1 = sstat[8 + row];
        float gir = i1 * (gi0 - m1 * c.Sg[d]) + c.cbg[d];
        float giz = i1 * (gi1 - m1 * c.Sg[512 + d]) + c.cbg[512 + d];
        float gig = i1 * (gi2v - m1 * c.Sg[1024 + d]) + c.cbg[1024 + d];
        float hr = ld4(c.gh2g + bb * 1536 + d) + c.bhh2[d];
        float hz = ld4(c.gh2g + bb * 1536 + 512 + d) + c.bhh2[512 + d];
        float hg = ld4(c.gh2g + bb * 1536 + 1024 + d) + c.bhh2[1024 + d];
        float r_ = sigf(gir + hr);
        float z_ = sigf(giz + hz);
        float n_ = tanhf(gig + r_ * hg);
        float hold = ld4(c.h2 + bb * 512 + d);
        float hnew = (1.f - z_) * n_ + z_ * hold;
        st4(c.h2 + bb * 512 + d, (t < declenI[bb]) ? hnew : hold);
        float h1r = (XS[row * 512 + d] - m1) * i1 * c.ln1g[d] + c.ln1b[d];
        float v2v = hnew + h1r;
        st4(c.v2 + bb * 512 + d, v2v);
        float ss = v2v, sq = v2v * v2v;
#pragma unroll
        for (int w = 1; w < 16; w <<= 1) { ss += __shfl_xor(ss, w); sq += __shfl_xor(sq, w); }
        if (dl == 0) {
          atomF(c.stats2 + (t & 1) * 128 + bb * 2, ss);
          atomF(c.stats2 + (t & 1) * 128 + bb * 2 + 1, sq);
        }
      }
      pfsink8(pw[0], pw[1], pw[2], pw[3], pw[4], pw[5], pw[6], pw[7]);
      pfsink2(pa0, pa1);
    }
    gridbar(c.leafs, c.root, ++ph);
  }
}

extern "C" void kernel_launch(void* const* d_in, const int* in_sizes, int n_in,
                              void* d_out, int out_size, void* d_ws, size_t ws_size,
                              hipStream_t stream) {
  (void)in_sizes; (void)n_in; (void)ws_size;
  Ctx c;
  c.enc = (const float*)d_in[0];
  c.caps_in = (const int*)d_in[1];
  c.lens_in = (const int*)d_in[2];
  c.eaw = (const float*)d_in[3];
  c.eab = (const float*)d_in[4];
  c.daw = (const float*)d_in[5];
  c.dab = (const float*)d_in[6];
  c.faw = (const float*)d_in[7];
  c.fab = (const float*)d_in[8];
  c.gw1 = (const float*)d_in[9];
  c.gb1 = (const float*)d_in[10];
  c.gw2 = (const float*)d_in[11];
  c.gb2 = (const float*)d_in[12];
  c.emb = (const float*)d_in[13];
  c.wih1 = (const float*)d_in[14];
  c.whh1 = (const float*)d_in[15];
  c.bih1 = (const float*)d_in[16];
  c.bhh1 = (const float*)d_in[17];
  c.wih2 = (const float*)d_in[18];
  c.whh2 = (const float*)d_in[19];
  c.bih2 = (const float*)d_in[20];
  c.bhh2 = (const float*)d_in[21];
  c.projw = (const float*)d_in[22];
  c.projb = (const float*)d_in[23];
  c.ln1g = (const float*)d_in[24];
  c.ln1b = (const float*)d_in[25];
  c.ln2g = (const float*)d_in[26];
  c.ln2b = (const float*)d_in[27];
  c.fw1 = (const float*)d_in[28];
  c.fb1 = (const float*)d_in[29];
  c.fw2 = (const float*)d_in[30];
  c.fb2 = (const float*)d_in[31];
  c.out = (float*)d_out;

  char* wp_ = (char*)d_ws;
  auto alloc = [&](size_t bytes) -> char* {
    char* p = wp_;
    wp_ += (bytes + 255) & ~(size_t)255;
    return p;
  };
  // zero-region (one memset): barriers | h1 | h2 | stats | att2acc | v2
  char* zbase = wp_;
  c.leafs = (int*)alloc(256 * 4);
  c.root = (int*)alloc(256);
  c.h1 = (float*)alloc((size_t)B * 512 * 4);
  c.h2 = (float*)alloc((size_t)B * 512 * 4);
  c.stats1 = (float*)alloc(2 * 64 * 2 * 4);
  c.stats2 = (float*)alloc(2 * 64 * 2 * 4);
  c.att2acc = (float*)alloc((size_t)B * 256 * 4);
  c.v2 = (float*)alloc((size_t)B * 512 * 4);
  size_t zbytes = (size_t)(wp_ - zbase);

  c.order_i = (int*)alloc(B * 4);
  c.declen = (int*)alloc(B * 4);
  c.caps_s = (int*)alloc((size_t)B * MAXLEN * 4);
  c.EaT = (float*)alloc((size_t)512 * 128 * 4);
  c.att1 = (float*)alloc((size_t)B * P * 128 * 4);
  c.v1 = (float*)alloc((size_t)B * 512 * 4);
  c.gin = (float*)alloc((size_t)B * 768 * 4);
  c.fgr = (float*)alloc((size_t)B * 1024 * 4);
  c.gh1g = (float*)alloc((size_t)B * 1536 * 4);
  c.gh2g = (float*)alloc((size_t)B * 1536 * 4);
  c.WA = (float*)alloc((size_t)32 * 65536 * 4);
  c.WB = (float*)alloc((size_t)32 * 49152 * 4);
  c.WC = (float*)alloc((size_t)32 * 24576 * 4);
  c.WD = (float*)alloc((size_t)32 * 65536 * 4);
  c.Watt = (float*)alloc((size_t)8 * 16384 * 4);
  c.Sf = (float*)alloc(1024 * 4);
  c.cbf = (float*)alloc(1024 * 4);
  c.Sg = (float*)alloc(1536 * 4);
  c.cbg = (float*)alloc(1536 * 4);

  hipMemsetAsync(d_out, 0, (size_t)out_size * 4, stream);
  hipMemsetAsync(zbase, 0, zbytes, stream);

  k_order<<<1, 64, 0, stream>>>(c);
  k_caps<<<(B * MAXLEN + 255) / 256, 256, 0, stream>>>(c);
  k_eat<<<(128 * 512 + 255) / 256, 256, 0, stream>>>(c);
  k_att1<<<(B * P) / 8, 256, 0, stream>>>(c);
  k_wpa<<<32, 256, 0, stream>>>(c);
  k_wpb<<<32, 256, 0, stream>>>(c);
  k_wpc<<<32, 256, 0, stream>>>(c);
  k_wpd<<<32, 256, 0, stream>>>(c);
  k_watt<<<8, 256, 0, stream>>>(c);
  k_consts<<<2560, 256, 0, stream>>>(c);

  persist<<<256, 512, 0, stream>>>(c);
}

// Round 5
// 11719.027 us; speedup vs baseline: 1.2272x; 1.2272x over previous
//
#include <hip/hip_runtime.h>
#include <math.h>

#define B 64
#define P 196
#define ENCD 512
#define DECD 512
#define EMBD 256
#define ATTD 128
#define FFND 1024
#define VV 2000
#define MAXLEN 160
#define TSTEPS 159
#define EPS 1e-5f

// output chunk offsets (flat f32)
#define OUT_PRED ((size_t)0)
#define OUT_CAPS ((size_t)(B * TSTEPS * VV))
#define OUT_DECL (OUT_CAPS + (size_t)(B * MAXLEN))
#define OUT_ALPH (OUT_DECL + (size_t)B)
#define OUT_ORDR (OUT_ALPH + (size_t)(B * TSTEPS * P))

// GEMM decomposition: 32 column-slices (cg=g&31, same-slice blocks share an XCD)
//                   x  8 row-groups of 8 rows (rg=g>>5, r0=rg*8)
// Weights are bf16-packed pairs in uint32, blocked [slice][kb8][cols][4 uints]
// so a wave's uint4 load covers 8 consecutive k for one column, 1KB contiguous
// per (kb8,128col) row. Per-XCD weight set = 4 slices x 400KB = 1.6MB -> L2-resident.
//   WA (P1: whh1|whh2|ln2g*fw1, 4096 cols, k=512): slice 32768 uints (128KB)
//   WB (P3: wih1|projw u=d*4+comp, 2048 cols, k=768): slice 24576 uints (96KB)
//   WC (P4: ln1g*wih2 u=d*3+comp, 1536 cols, k=512): slice 12288 uints (48KB)
//   WD (P2: fw2 padded 2048 cols, k=1024): slice 32768 uints (128KB)
//   Watt (att2|gate1, 256 cols, k-sliced 8x64): fp32 [ks][kb][256][4] (64KB/ks)

struct Ctx {
  const float* enc; const int* caps_in; const int* lens_in;
  const float* eaw; const float* eab; const float* daw; const float* dab;
  const float* faw; const float* fab;
  const float* gw1; const float* gb1; const float* gw2; const float* gb2;
  const float* emb;
  const float* wih1; const float* whh1; const float* bih1; const float* bhh1;
  const float* wih2; const float* whh2; const float* bih2; const float* bhh2;
  const float* projw; const float* projb;
  const float* ln1g; const float* ln1b; const float* ln2g; const float* ln2b;
  const float* fw1; const float* fb1; const float* fw2; const float* fb2;
  // ws
  int* leafs; int* root;
  int* order_i; int* declen; int* caps_s;
  float* EaT; float* att1;
  float* h1; float* h2; float* v1; float* v2;
  float* gin; float* fgr; float* gh1g; float* gh2g; float* att2acc;
  float* stats1; float* stats2;   // [2][64][2]
  unsigned int* WA; unsigned int* WB; unsigned int* WC; unsigned int* WD;
  float* Watt;
  float* Sf; float* cbf; float* Sg; float* cbg;
  float* out;
};

__device__ __forceinline__ float sigf(float x) { return 1.f / (1.f + __expf(-x)); }

// ---- device-coherent (MALL) helpers: relaxed agent atomics => sc1, no cache flushes
__device__ __forceinline__ float ld4(const float* p) {
  unsigned int u = __hip_atomic_load((const unsigned int*)p, __ATOMIC_RELAXED, __HIP_MEMORY_SCOPE_AGENT);
  return __uint_as_float(u);
}
__device__ __forceinline__ void st4(float* p, float v) {
  __hip_atomic_store((unsigned int*)p, __float_as_uint(v), __ATOMIC_RELAXED, __HIP_MEMORY_SCOPE_AGENT);
}
__device__ __forceinline__ void st8(float* p, float a, float b2) {
  unsigned long long v = ((unsigned long long)__float_as_uint(b2) << 32) | (unsigned long long)__float_as_uint(a);
  __hip_atomic_store((unsigned long long*)p, v, __ATOMIC_RELAXED, __HIP_MEMORY_SCOPE_AGENT);
}
__device__ __forceinline__ void atomF(float* p, float v) {
  __hip_atomic_fetch_add(p, v, __ATOMIC_RELAXED, __HIP_MEMORY_SCOPE_AGENT);
}
// 16B coherent load: issue many, then one vmwait()
__device__ __forceinline__ float4 ldg16(const float* p) {
  float4 d;
  asm volatile("global_load_dwordx4 %0, %1, off sc0 sc1" : "=v"(d) : "v"(p));
  return d;
}
__device__ __forceinline__ void vmwait() { asm volatile("s_waitcnt vmcnt(0)" ::: "memory"); }

__device__ __forceinline__ unsigned short tobf(float x) {
  unsigned int u = __float_as_uint(x);
  u += 0x7fffu + ((u >> 16) & 1u);
  return (unsigned short)(u >> 16);
}
__device__ __forceinline__ float frombf(unsigned short s) {
  return __uint_as_float(((unsigned int)s) << 16);
}
__device__ __forceinline__ unsigned int pack2bf(float a, float b) {
  return (unsigned int)tobf(a) | ((unsigned int)tobf(b) << 16);
}
// unpack a uint holding two bf16 (low = even k, high = odd k)
__device__ __forceinline__ void bf2(unsigned int u, float& a, float& b) {
  a = __uint_as_float(u << 16);
  b = __uint_as_float(u & 0xffff0000u);
}

// ---------------- setup kernels ----------------

__global__ void k_order(Ctx c) {
  __shared__ int lens[B];
  int tid = threadIdx.x;
  lens[tid] = c.lens_in[tid];
  __syncthreads();
  int li = lens[tid];
  int pos = 0;
  for (int j = 0; j < B; ++j) {
    int lj = lens[j];
    pos += (lj > li || (lj == li && j < tid)) ? 1 : 0;
  }
  c.order_i[pos] = tid;
  c.declen[pos] = li - 1;
  c.out[OUT_ORDR + pos] = (float)tid;
  c.out[OUT_DECL + pos] = (float)(li - 1);
}

__global__ __launch_bounds__(256) void k_caps(Ctx c) {
  int idx = blockIdx.x * 256 + threadIdx.x;
  if (idx < B * MAXLEN) {
    int b = idx / MAXLEN, t = idx - b * MAXLEN;
    int v = c.caps_in[c.order_i[b] * MAXLEN + t];
    c.caps_s[idx] = v;
    c.out[OUT_CAPS + idx] = (float)v;
  }
}

__global__ __launch_bounds__(256) void k_eat(Ctx c) {
  int idx = blockIdx.x * 256 + threadIdx.x;
  if (idx < 128 * 512) {
    int k = idx >> 7, d = idx & 127;
    c.EaT[(size_t)k * 128 + d] = c.eaw[(size_t)d * 512 + k];
  }
}

__global__ __launch_bounds__(256) void k_att1(Ctx c) {
  __shared__ float Xs[8 * 512];
  int tid = threadIdx.x;
  int r0 = blockIdx.x * 8;
  for (int idx = tid; idx < 8 * 512; idx += 256) {
    int rr = idx >> 9, k = idx & 511;
    int r = r0 + rr;
    int b = r / P, p = r - b * P;
    int ob = c.order_i[b];
    Xs[idx] = c.enc[((size_t)(ob * P + p)) * ENCD + k];
  }
  __syncthreads();
  int d = tid >> 1, kh = tid & 1;
  float acc[8];
#pragma unroll
  for (int rr = 0; rr < 8; ++rr) acc[rr] = 0.f;
  int kbase = kh * 256;
  for (int k = 0; k < 256; ++k) {
    float w = c.EaT[(size_t)(kbase + k) * 128 + d];
#pragma unroll
    for (int rr = 0; rr < 8; ++rr) acc[rr] = fmaf(w, Xs[rr * 512 + kbase + k], acc[rr]);
  }
#pragma unroll
  for (int rr = 0; rr < 8; ++rr) {
    acc[rr] += __shfl_xor(acc[rr], 1);
    if (kh == 0) c.att1[(size_t)(r0 + rr) * 128 + d] = acc[rr];
  }
}

__device__ __forceinline__ float wa_elem(const Ctx& c, int col, int k) {
  if (col < 1536) return c.whh1[(size_t)col * 512 + k];
  if (col < 3072) return c.whh2[(size_t)(col - 1536) * 512 + k];
  return c.ln2g[k] * c.fw1[(size_t)(col - 3072) * 512 + k];
}

__global__ __launch_bounds__(256) void k_wpa(Ctx c) {
  int s = blockIdx.x;
  unsigned int* dst = c.WA + (size_t)s * 32768;
  for (int idx = threadIdx.x; idx < 32768; idx += 256) {
    int kb8 = idx >> 9, r = idx & 511, cc = r >> 2, jw = r & 3;
    int col = s * 128 + cc, k0 = kb8 * 8 + jw * 2;
    dst[idx] = pack2bf(wa_elem(c, col, k0), wa_elem(c, col, k0 + 1));
  }
}

__device__ __forceinline__ float wb_elem(const Ctx& c, int u, int k) {
  int d = u >> 2, comp = u & 3;
  return (comp < 3) ? c.wih1[(size_t)(comp * 512 + d) * 768 + k]
                    : c.projw[(size_t)d * 768 + k];
}

__global__ __launch_bounds__(256) void k_wpb(Ctx c) {
  int s = blockIdx.x;
  unsigned int* dst = c.WB + (size_t)s * 24576;
  for (int idx = threadIdx.x; idx < 24576; idx += 256) {
    int kb8 = idx >> 8, r = idx & 255, cc = r >> 2, jw = r & 3;
    int u = s * 64 + cc, k0 = kb8 * 8 + jw * 2;
    dst[idx] = pack2bf(wb_elem(c, u, k0), wb_elem(c, u, k0 + 1));
  }
}

__device__ __forceinline__ float wc_elem(const Ctx& c, int u, int k) {
  int d = u / 3, comp = u - d * 3;
  return c.ln1g[k] * c.wih2[(size_t)(comp * 512 + d) * 512 + k];
}

__global__ __launch_bounds__(256) void k_wpc(Ctx c) {
  int s = blockIdx.x;
  unsigned int* dst = c.WC + (size_t)s * 12288;
  for (int idx = threadIdx.x; idx < 12288; idx += 256) {
    int kb8 = idx / 192, r = idx - kb8 * 192, cc = r >> 2, jw = r & 3;
    int u = s * 48 + cc, k0 = kb8 * 8 + jw * 2;
    dst[idx] = pack2bf(wc_elem(c, u, k0), wc_elem(c, u, k0 + 1));
  }
}

__device__ __forceinline__ float wd_elem(const Ctx& c, int vcol, int k) {
  return (vcol < 2000) ? c.fw2[(size_t)vcol * 1024 + k] : 0.f;
}

__global__ __launch_bounds__(256) void k_wpd(Ctx c) {
  int s = blockIdx.x;
  unsigned int* dst = c.WD + (size_t)s * 32768;
  for (int idx = threadIdx.x; idx < 32768; idx += 256) {
    int kb8 = idx >> 8, r = idx & 255, cc = r >> 2, jw = r & 3;
    int vcol = s * 64 + cc, k0 = kb8 * 8 + jw * 2;
    dst[idx] = pack2bf(wd_elem(c, vcol, k0), wd_elem(c, vcol, k0 + 1));
  }
}

__global__ __launch_bounds__(256) void k_watt(Ctx c) {
  int ks = blockIdx.x;
  float* dst = c.Watt + (size_t)ks * 16384;
  for (int idx = threadIdx.x; idx < 16384; idx += 256) {
    int kb = idx >> 10, r = idx & 1023, cc = r >> 2, jj = r & 3;
    int k = ks * 64 + kb * 4 + jj;
    dst[idx] = (cc < 128) ? c.daw[(size_t)cc * 512 + k] : c.gw1[(size_t)(cc - 128) * 512 + k];
  }
}

// Sf/Sg must be the column-sums of the QUANTIZED folded weights so the
// LN mean-subtraction stays exact w.r.t. quantization.
__global__ __launch_bounds__(256) void k_consts(Ctx c) {
  __shared__ float r1[256], r2[256];
  int i = blockIdx.x, tid = threadIdx.x;
  float a = 0.f, b2 = 0.f;
  if (i < 1024) {
    const float* w = c.fw1 + (size_t)i * 512;
    for (int k = tid; k < 512; k += 256) {
      a += frombf(tobf(c.ln2g[k] * w[k]));
      b2 = fmaf(c.ln2b[k], w[k], b2);
    }
  } else {
    const float* w = c.wih2 + (size_t)(i - 1024) * 512;
    for (int k = tid; k < 512; k += 256) {
      a += frombf(tobf(c.ln1g[k] * w[k]));
      b2 = fmaf(c.ln1b[k], w[k], b2);
    }
  }
  r1[tid] = a; r2[tid] = b2;
  __syncthreads();
  for (int s = 128; s > 0; s >>= 1) {
    if (tid < s) { r1[tid] += r1[tid + s]; r2[tid] += r2[tid + s]; }
    __syncthreads();
  }
  if (tid == 0) {
    if (i < 1024) { c.Sf[i] = r1[0]; c.cbf[i] = r2[0] + c.fb1[i]; }
    else { c.Sg[i - 1024] = r1[0]; c.cbg[i - 1024] = r2[0] + c.bih2[i - 1024]; }
  }
}

// ---------------- persistent kernel ----------------

__device__ __forceinline__ void gridbar(int* leafs, int* root, int ph) {
  __builtin_amdgcn_s_waitcnt(0);   // drain this wave's sc1 stores (acked at MALL)
  __syncthreads();
  if (threadIdx.x == 0) {
    int old = __hip_atomic_fetch_add(&leafs[(blockIdx.x & 7) * 32], 1,
                                     __ATOMIC_RELAXED, __HIP_MEMORY_SCOPE_AGENT);
    if (old == ph * 32 - 1)
      __hip_atomic_fetch_add(root, 1, __ATOMIC_RELAXED, __HIP_MEMORY_SCOPE_AGENT);
    while (__hip_atomic_load(root, __ATOMIC_RELAXED, __HIP_MEMORY_SCOPE_AGENT) < ph * 8)
      __builtin_amdgcn_s_sleep(1);
  }
  __syncthreads();
}

__global__ __launch_bounds__(512) void persist(Ctx c) {
  __shared__ unsigned short att1L[196 * 130];  // bf16, row-padded (+2)
  __shared__ unsigned short encL[196 * 128];   // bf16
  __shared__ float SH[12288];                  // XS | RED union (per-phase split)
  __shared__ float eL[256];
  __shared__ float alphaL[256];
  __shared__ float att2sL[128], fawL[128], dabL[128], gb1L[128], gw2L[128];
  __shared__ float wred[16];
  __shared__ float sstat[16];
  __shared__ int declenI[64];
  __shared__ float gb2v, fabv;

  const int g = blockIdx.x;
  const int tid = threadIdx.x;
  const int cg = g & 31;         // column slice (same-slice blocks share an XCD)
  const int rg = g >> 5;         // 8 row-groups of 8 rows
  const int r0 = rg * 8;
  const int bA = g >> 2, q = g & 3;  // attention mapping
  const int kc = tid >> 6;       // wave index = k-chunk (wave-uniform x broadcast)
  const int ct = tid & 63;       // lane = column(s)

  // ---- one-time staging ----
  if (tid < 128) {
    fawL[tid] = c.faw[tid];
    dabL[tid] = c.dab[tid] + c.eab[tid];
    gb1L[tid] = c.gb1[tid];
    gw2L[tid] = c.gw2[tid];
  }
  if (tid == 0) { gb2v = c.gb2[0]; fabv = c.fab[0]; }
  if (tid < 64) declenI[tid] = c.declen[tid];
  {
    const int ob = c.order_i[bA];
    for (int idx = tid; idx < 196 * 128; idx += 512) {
      int p = idx >> 7, j = idx & 127;
      att1L[p * 130 + j] = tobf(c.att1[((size_t)bA * P + p) * 128 + j]);
      encL[idx] = tobf(c.enc[((size_t)(ob * P + p)) * 512 + q * 128 + j]);
    }
  }
  __syncthreads();

  int ph = 0;
  for (int t = 0; t < MAXLEN; ++t) {
    // ===== PHASE1: gh1 | gh2 | fg(LN2-folded,relu) + att2/gate k-split ========
    {
      float* XS = SH;            // 4096 f (8 rows x 512, this slice's region)
      float* RED = SH + 4096;    // 8192 f (8kc x 8row x 128col)
      const float* hsrc = ((cg < 12) ? c.h1 : (cg < 24) ? c.h2 : c.v2) + (size_t)r0 * 512;
      float4 s0 = ldg16(hsrc + tid * 4);
      float4 s1 = ldg16(hsrc + 2048 + tid * 4);
      if (tid < 8) {
        int slot = (t + 1) & 1;
        float a = ld4(c.stats2 + slot * 128 + (r0 + tid) * 2);
        float b2 = ld4(c.stats2 + slot * 128 + (r0 + tid) * 2 + 1);
        float m = a * (1.f / 512.f);
        float va = b2 * (1.f / 512.f) - m * m;
        sstat[tid] = m; sstat[8 + tid] = rsqrtf(va + EPS);
      }
      vmwait();
      *(float4*)(XS + tid * 4) = s0;
      *(float4*)(XS + 2048 + tid * 4) = s1;
      __syncthreads();

      {
        const unsigned int* wp = c.WA + (size_t)cg * 32768 + (size_t)kc * 4096 + ct * 4;
        const float* xb = XS + kc * 64;
        float acc[8][2];
#pragma unroll
        for (int r = 0; r < 8; ++r) { acc[r][0] = 0.f; acc[r][1] = 0.f; }
#pragma unroll 2
        for (int i = 0; i < 8; ++i) {
          uint4 u0 = *(const uint4*)(wp + i * 512);
          uint4 u1 = *(const uint4*)(wp + i * 512 + 256);
          float wa[8], wb[8];
          bf2(u0.x, wa[0], wa[1]); bf2(u0.y, wa[2], wa[3]);
          bf2(u0.z, wa[4], wa[5]); bf2(u0.w, wa[6], wa[7]);
          bf2(u1.x, wb[0], wb[1]); bf2(u1.y, wb[2], wb[3]);
          bf2(u1.z, wb[4], wb[5]); bf2(u1.w, wb[6], wb[7]);
#pragma unroll
          for (int r = 0; r < 8; ++r) {
            float4 x0 = *(const float4*)(xb + r * 512 + i * 8);
            float4 x1 = *(const float4*)(xb + r * 512 + i * 8 + 4);
            acc[r][0] = fmaf(wa[0], x0.x, fmaf(wa[1], x0.y, fmaf(wa[2], x0.z, fmaf(wa[3], x0.w, acc[r][0]))));
            acc[r][0] = fmaf(wa[4], x1.x, fmaf(wa[5], x1.y, fmaf(wa[6], x1.z, fmaf(wa[7], x1.w, acc[r][0]))));
            acc[r][1] = fmaf(wb[0], x0.x, fmaf(wb[1], x0.y, fmaf(wb[2], x0.z, fmaf(wb[3], x0.w, acc[r][1]))));
            acc[r][1] = fmaf(wb[4], x1.x, fmaf(wb[5], x1.y, fmaf(wb[6], x1.z, fmaf(wb[7], x1.w, acc[r][1]))));
          }
        }
#pragma unroll
        for (int r = 0; r < 8; ++r) {
          RED[(kc * 8 + r) * 128 + ct] = acc[r][0];
          RED[(kc * 8 + r) * 128 + ct + 64] = acc[r][1];
        }
      }
      // att2 (daw) + gate1 (gw1): k-sliced across the 8 h2-region slices 16..23,
      // accumulated into att2acc via device-scope atomics (zeroed each P3).
      if (cg >= 16 && cg < 24) {
        const int ks_att = cg - 16;
        const int ct2 = tid >> 1, half = tid & 1;
        const float* wp = c.Watt + (size_t)ks_att * 16384 + half * 8192 + ct2 * 4;
        const float* xb = XS + ks_att * 64 + half * 32;
        float a[8];
#pragma unroll
        for (int r = 0; r < 8; ++r) a[r] = 0.f;
#pragma unroll
        for (int i = 0; i < 8; ++i) {
          float4 w = *(const float4*)(wp + i * 1024);
#pragma unroll
          for (int r = 0; r < 8; ++r) {
            float4 x = *(const float4*)(xb + r * 512 + i * 4);
            a[r] = fmaf(w.x, x.x, fmaf(w.y, x.y, fmaf(w.z, x.z, fmaf(w.w, x.w, a[r]))));
          }
        }
#pragma unroll
        for (int r = 0; r < 8; ++r) {
          a[r] += __shfl_xor(a[r], 1);
          if (half == 0) atomF(c.att2acc + (r0 + r) * 256 + ct2, a[r]);
        }
      }
      __syncthreads();
      {
        int row = tid >> 6, cp = (tid & 63) * 2;
        float s0_ = 0.f, s1_ = 0.f;
#pragma unroll
        for (int k8 = 0; k8 < 8; ++k8) {
          float2 v = *(const float2*)(RED + (k8 * 8 + row) * 128 + cp);
          s0_ += v.x; s1_ += v.y;
        }
        int bb = r0 + row;
        int gcol = cg * 128 + cp;
        if (cg < 12) st8(c.gh1g + bb * 1536 + gcol, s0_, s1_);
        else if (cg < 24) st8(c.gh2g + bb * 1536 + (gcol - 1536), s0_, s1_);
        else {
          int cf = gcol - 3072;
          float m2 = sstat[row], i2 = sstat[8 + row];
          float v0 = i2 * (s0_ - m2 * c.Sf[cf]) + c.cbf[cf];
          float v1v = i2 * (s1_ - m2 * c.Sf[cf + 1]) + c.cbf[cf + 1];
          st8(c.fgr + bb * 1024 + cf, fmaxf(v0, 0.f), fmaxf(v1v, 0.f));
        }
      }
    }
    gridbar(c.leafs, c.root, ++ph);

    // ===== PHASE2: preds GEMM (store t-1) + stats zero + full attention + gin ===
    {
      float* XS = SH;            // 8192 f (8 rows x 1024 fgr)
      float* RED = SH + 8192;    // 4096 f
      const float* fsrc = c.fgr + (size_t)r0 * 1024;
      float4 s0 = ldg16(fsrc + tid * 4);
      float4 s1 = ldg16(fsrc + 2048 + tid * 4);
      float4 s2 = ldg16(fsrc + 4096 + tid * 4);
      float4 s3 = ldg16(fsrc + 6144 + tid * 4);
      float a2r = 0.f, g1r = 0.f;
      if (tid < 128) {
        a2r = ld4(c.att2acc + bA * 256 + tid);
        g1r = ld4(c.att2acc + bA * 256 + 128 + tid);
      }
      if (g == 0) {
        int sl = t & 1;
        if (tid < 128) st4(c.stats1 + sl * 128 + tid, 0.f);
        else if (tid < 256) st4(c.stats2 + sl * 128 + (tid - 128), 0.f);
      }
      vmwait();
      *(float4*)(XS + tid * 4) = s0;
      *(float4*)(XS + 2048 + tid * 4) = s1;
      *(float4*)(XS + 4096 + tid * 4) = s2;
      *(float4*)(XS + 6144 + tid * 4) = s3;
      if (tid < 128) {
        att2sL[tid] = a2r + dabL[tid];
        float g1 = fmaxf(g1r + gb1L[tid], 0.f);
        float gv = g1 * gw2L[tid];
#pragma unroll
        for (int w = 1; w < 64; w <<= 1) gv += __shfl_xor(gv, w);
        if ((tid & 63) == 0) wred[tid >> 6] = gv;
      }
      __syncthreads();   // S1: XS + att2sL + wred[0..1]

      {
        const unsigned int* wp = c.WD + (size_t)cg * 32768 + (size_t)kc * 4096 + ct * 4;
        const float* xb = XS + kc * 128;
        float acc[8];
#pragma unroll
        for (int r = 0; r < 8; ++r) acc[r] = 0.f;
#pragma unroll 4
        for (int i = 0; i < 16; ++i) {
          uint4 u = *(const uint4*)(wp + i * 256);
          float w8[8];
          bf2(u.x, w8[0], w8[1]); bf2(u.y, w8[2], w8[3]);
          bf2(u.z, w8[4], w8[5]); bf2(u.w, w8[6], w8[7]);
#pragma unroll
          for (int r = 0; r < 8; ++r) {
            float4 x0 = *(const float4*)(xb + r * 1024 + i * 8);
            float4 x1 = *(const float4*)(xb + r * 1024 + i * 8 + 4);
            acc[r] = fmaf(w8[0], x0.x, fmaf(w8[1], x0.y, fmaf(w8[2], x0.z, fmaf(w8[3], x0.w, acc[r]))));
            acc[r] = fmaf(w8[4], x1.x, fmaf(w8[5], x1.y, fmaf(w8[6], x1.z, fmaf(w8[7], x1.w, acc[r]))));
          }
        }
#pragma unroll
        for (int r = 0; r < 8; ++r) RED[(kc * 8 + r) * 64 + ct] = acc[r];
      }
      __syncthreads();   // S2: RED ready
      {
        int row = tid >> 6, cl = tid & 63;
        float s = 0.f;
#pragma unroll
        for (int k8 = 0; k8 < 8; ++k8) s += RED[(k8 * 8 + row) * 64 + cl];
        int bb = r0 + row, vcol = cg * 64 + cl;
        if (vcol < 2000 && t > 0 && (t - 1) < declenI[bb])
          c.out[OUT_PRED + ((size_t)bb * TSTEPS + (t - 1)) * VV + vcol] = s + c.fb2[vcol];
      }
      // ---- attention (per b=bA, redundant across the 4 q-blocks) ----
      {
        int p = tid >> 1, jh = tid & 1;
        float e = 0.f;
        if (p < 196) {
          const unsigned short* ap = att1L + p * 130 + jh * 64;
#pragma unroll 8
          for (int j = 0; j < 64; ++j)
            e = fmaf(fmaxf(frombf(ap[j]) + att2sL[jh * 64 + j], 0.f), fawL[jh * 64 + j], e);
        }
        e += __shfl_xor(e, 1);
        if (jh == 0 && p < 196) eL[p] = e + fabv;
      }
      __syncthreads();   // S3: eL ready (also RED reads done before awe reuse)
      float ev = (tid < 196) ? eL[tid] : -3.0e38f;
      if (tid < 256) {
        float mv = ev;
#pragma unroll
        for (int w = 1; w < 64; w <<= 1) mv = fmaxf(mv, __shfl_xor(mv, w));
        if ((tid & 63) == 0) wred[2 + (tid >> 6)] = mv;
      }
      __syncthreads();   // S4
      float mx = fmaxf(fmaxf(wred[2], wred[3]), fmaxf(wred[4], wred[5]));
      float ex = (tid < 196) ? __expf(ev - mx) : 0.f;
      if (tid < 256) {
        float sv = ex;
#pragma unroll
        for (int w = 1; w < 64; w <<= 1) sv += __shfl_xor(sv, w);
        if ((tid & 63) == 0) wred[6 + (tid >> 6)] = sv;
      }
      __syncthreads();   // S5
      float inv = 1.f / (wred[6] + wred[7] + wred[8] + wred[9]);
      float gate = sigf(wred[0] + wred[1] + gb2v);
      if (tid < 256) alphaL[tid] = ex * inv;
      if (q == 0 && tid < 196 && t < declenI[bA])
        c.out[OUT_ALPH + ((size_t)bA * TSTEPS + t) * P + tid] = ex * inv;
      __syncthreads();   // S6: alphaL ready
      {
        int el = tid & 127, pq = tid >> 7;
        const unsigned short* ep2 = encL + (size_t)(pq * 49) * 128 + el;
        const float* alp = alphaL + pq * 49;
        float s_ = 0.f;
#pragma unroll
        for (int i = 0; i < 49; ++i) s_ = fmaf(alp[i], frombf(ep2[(size_t)i * 128]), s_);
        RED[tid] = s_;
      }
      __syncthreads();   // S7
      if (tid < 128) {
        float aw = RED[tid] + RED[128 + tid] + RED[256 + tid] + RED[384 + tid];
        st4(c.gin + bA * 768 + 256 + q * 128 + tid, aw * gate);
      }
      if (q == 1 && tid < 256) {
        int tok = c.caps_s[bA * MAXLEN + t];
        st4(c.gin + bA * 768 + tid, c.emb[(size_t)tok * 256 + tid]);
      }
    }
    gridbar(c.leafs, c.root, ++ph);

    // ===== PHASE3: gin GEMM + GRU1 + v1 + stats1 (+ att2acc zero) ==============
    {
      float* XS = SH;            // 6144 f (8 rows x 768 gin)
      float* RED = SH + 6144;    // 4096 f
      const float* gsrc = c.gin + (size_t)r0 * 768;
      float4 s0 = ldg16(gsrc + tid * 4);
      float4 s1 = ldg16(gsrc + 2048 + tid * 4);
      float4 s2 = ldg16(gsrc + 4096 + tid * 4);
      if (g < 32) st4(c.att2acc + g * 512 + tid, 0.f);
      vmwait();
      *(float4*)(XS + tid * 4) = s0;
      *(float4*)(XS + 2048 + tid * 4) = s1;
      *(float4*)(XS + 4096 + tid * 4) = s2;
      __syncthreads();

      {
        const unsigned int* wp = c.WB + (size_t)cg * 24576 + (size_t)kc * 3072 + ct * 4;
        const float* xb = XS + kc * 96;
        float acc[8];
#pragma unroll
        for (int r = 0; r < 8; ++r) acc[r] = 0.f;
#pragma unroll 4
        for (int i = 0; i < 12; ++i) {
          uint4 u = *(const uint4*)(wp + i * 256);
          float w8[8];
          bf2(u.x, w8[0], w8[1]); bf2(u.y, w8[2], w8[3]);
          bf2(u.z, w8[4], w8[5]); bf2(u.w, w8[6], w8[7]);
#pragma unroll
          for (int r = 0; r < 8; ++r) {
            float4 x0 = *(const float4*)(xb + r * 768 + i * 8);
            float4 x1 = *(const float4*)(xb + r * 768 + i * 8 + 4);
            acc[r] = fmaf(w8[0], x0.x, fmaf(w8[1], x0.y, fmaf(w8[2], x0.z, fmaf(w8[3], x0.w, acc[r]))));
            acc[r] = fmaf(w8[4], x1.x, fmaf(w8[5], x1.y, fmaf(w8[6], x1.z, fmaf(w8[7], x1.w, acc[r]))));
          }
        }
#pragma unroll
        for (int r = 0; r < 8; ++r) RED[(kc * 8 + r) * 64 + ct] = acc[r];
      }
      __syncthreads();
      if (tid < 128) {
        int row = tid >> 4, dl = tid & 15;
        int bb = r0 + row, d = cg * 16 + dl;
        float gi0 = 0.f, gi1 = 0.f, gi2v = 0.f, gi3 = 0.f;
#pragma unroll
        for (int k8 = 0; k8 < 8; ++k8) {
          float4 v = *(const float4*)(RED + (k8 * 8 + row) * 64 + dl * 4);
          gi0 += v.x; gi1 += v.y; gi2v += v.z; gi3 += v.w;
        }
        float gir = gi0 + c.bih1[d];
        float giz = gi1 + c.bih1[512 + d];
        float gig = gi2v + c.bih1[1024 + d];
        float pj = gi3 + c.projb[d];
        float hr = ld4(c.gh1g + bb * 1536 + d) + c.bhh1[d];
        float hz = ld4(c.gh1g + bb * 1536 + 512 + d) + c.bhh1[512 + d];
        float hg = ld4(c.gh1g + bb * 1536 + 1024 + d) + c.bhh1[1024 + d];
        float r_ = sigf(gir + hr);
        float z_ = sigf(giz + hz);
        float n_ = tanhf(gig + r_ * hg);
        float hold = ld4(c.h1 + bb * 512 + d);
        float hnew = (1.f - z_) * n_ + z_ * hold;
        st4(c.h1 + bb * 512 + d, (t < declenI[bb]) ? hnew : hold);
        float v1v = hnew + pj;
        st4(c.v1 + bb * 512 + d, v1v);
        float ss = v1v, sq = v1v * v1v;
#pragma unroll
        for (int w = 1; w < 16; w <<= 1) { ss += __shfl_xor(ss, w); sq += __shfl_xor(sq, w); }
        if (dl == 0) {
          atomF(c.stats1 + (t & 1) * 128 + bb * 2, ss);
          atomF(c.stats1 + (t & 1) * 128 + bb * 2 + 1, sq);
        }
      }
    }
    gridbar(c.leafs, c.root, ++ph);

    // ===== PHASE4: gi2 GEMM (LN1-folded) + GRU2 + v2 + stats2 ==================
    {
      float* XS = SH;            // 4096 f (8 rows x 512 v1)
      float* RED = SH + 4096;    // 3072 f
      const float* vsrc = c.v1 + (size_t)r0 * 512;
      float4 s0 = ldg16(vsrc + tid * 4);
      float4 s1 = ldg16(vsrc + 2048 + tid * 4);
      if (tid < 8) {
        float a = ld4(c.stats1 + (t & 1) * 128 + (r0 + tid) * 2);
        float b2 = ld4(c.stats1 + (t & 1) * 128 + (r0 + tid) * 2 + 1);
        float m = a * (1.f / 512.f);
        float va = b2 * (1.f / 512.f) - m * m;
        sstat[tid] = m; sstat[8 + tid] = rsqrtf(va + EPS);
      }
      vmwait();
      *(float4*)(XS + tid * 4) = s0;
      *(float4*)(XS + 2048 + tid * 4) = s1;
      __syncthreads();

      if (ct < 48) {
        const unsigned int* wp = c.WC + (size_t)cg * 12288 + (size_t)kc * 1536 + ct * 4;
        const float* xb = XS + kc * 64;
        float acc[8];
#pragma unroll
        for (int r = 0; r < 8; ++r) acc[r] = 0.f;
#pragma unroll 2
        for (int i = 0; i < 8; ++i) {
          uint4 u = *(const uint4*)(wp + i * 192);
          float w8[8];
          bf2(u.x, w8[0], w8[1]); bf2(u.y, w8[2], w8[3]);
          bf2(u.z, w8[4], w8[5]); bf2(u.w, w8[6], w8[7]);
#pragma unroll
          for (int r = 0; r < 8; ++r) {
            float4 x0 = *(const float4*)(xb + r * 512 + i * 8);
            float4 x1 = *(const float4*)(xb + r * 512 + i * 8 + 4);
            acc[r] = fmaf(w8[0], x0.x, fmaf(w8[1], x0.y, fmaf(w8[2], x0.z, fmaf(w8[3], x0.w, acc[r]))));
            acc[r] = fmaf(w8[4], x1.x, fmaf(w8[5], x1.y, fmaf(w8[6], x1.z, fmaf(w8[7], x1.w, acc[r]))));
          }
        }
#pragma unroll
        for (int r = 0; r < 8; ++r) RED[(kc * 8 + r) * 48 + ct] = acc[r];
      }
      __syncthreads();
      if (tid < 128) {
        int row = tid >> 4, dl = tid & 15;
        int bb = r0 + row, d = cg * 16 + dl;
        float gi0 = 0.f, gi1 = 0.f, gi2v = 0.f;
#pragma unroll
        for (int k8 = 0; k8 < 8; ++k8) {
          const float* rp = RED + (k8 * 8 + row) * 48 + dl * 3;
          gi0 += rp[0]; gi1 += rp[1]; gi2v += rp[2];
        }
        float m1 = sstat[row], i1 = sstat[8 + row];
        float gir = i1 * (gi0 - m1 * c.Sg[d]) + c.cbg[d];
        float giz = i1 * (gi1 - m1 * c.Sg[512 + d]) + c.cbg[512 + d];
        float gig = i1 * (gi2v - m1 * c.Sg[1024 + d]) + c.cbg[1024 + d];
        float hr = ld4(c.gh2g + bb * 1536 + d) + c.bhh2[d];
        float hz = ld4(c.gh2g + bb * 1536 + 512 + d) + c.bhh2[512 + d];
        float hg = ld4(c.gh2g + bb * 1536 + 1024 + d) + c.bhh2[1024 + d];
        float r_ = sigf(gir + hr);
        float z_ = sigf(giz + hz);
        float n_ = tanhf(gig + r_ * hg);
        float hold = ld4(c.h2 + bb * 512 + d);
        float hnew = (1.f - z_) * n_ + z_ * hold;
        st4(c.h2 + bb * 512 + d, (t < declenI[bb]) ? hnew : hold);
        float h1r = (XS[row * 512 + d] - m1) * i1 * c.ln1g[d] + c.ln1b[d];
        float v2v = hnew + h1r;
        st4(c.v2 + bb * 512 + d, v2v);
        float ss = v2v, sq = v2v * v2v;
#pragma unroll
        for (int w = 1; w < 16; w <<= 1) { ss += __shfl_xor(ss, w); sq += __shfl_xor(sq, w); }
        if (dl == 0) {
          atomF(c.stats2 + (t & 1) * 128 + bb * 2, ss);
          atomF(c.stats2 + (t & 1) * 128 + bb * 2 + 1, sq);
        }
      }
    }
    gridbar(c.leafs, c.root, ++ph);
  }
}

extern "C" void kernel_launch(void* const* d_in, const int* in_sizes, int n_in,
                              void* d_out, int out_size, void* d_ws, size_t ws_size,
                              hipStream_t stream) {
  (void)in_sizes; (void)n_in; (void)ws_size;
  Ctx c;
  c.enc = (const float*)d_in[0];
  c.caps_in = (const int*)d_in[1];
  c.lens_in = (const int*)d_in[2];
  c.eaw = (const float*)d_in[3];
  c.eab = (const float*)d_in[4];
  c.daw = (const float*)d_in[5];
  c.dab = (const float*)d_in[6];
  c.faw = (const float*)d_in[7];
  c.fab = (const float*)d_in[8];
  c.gw1 = (const float*)d_in[9];
  c.gb1 = (const float*)d_in[10];
  c.gw2 = (const float*)d_in[11];
  c.gb2 = (const float*)d_in[12];
  c.emb = (const float*)d_in[13];
  c.wih1 = (const float*)d_in[14];
  c.whh1 = (const float*)d_in[15];
  c.bih1 = (const float*)d_in[16];
  c.bhh1 = (const float*)d_in[17];
  c.wih2 = (const float*)d_in[18];
  c.whh2 = (const float*)d_in[19];
  c.bih2 = (const float*)d_in[20];
  c.bhh2 = (const float*)d_in[21];
  c.projw = (const float*)d_in[22];
  c.projb = (const float*)d_in[23];
  c.ln1g = (const float*)d_in[24];
  c.ln1b = (const float*)d_in[25];
  c.ln2g = (const float*)d_in[26];
  c.ln2b = (const float*)d_in[27];
  c.fw1 = (const float*)d_in[28];
  c.fb1 = (const float*)d_in[29];
  c.fw2 = (const float*)d_in[30];
  c.fb2 = (const float*)d_in[31];
  c.out = (float*)d_out;

  char* wp_ = (char*)d_ws;
  auto alloc = [&](size_t bytes) -> char* {
    char* p = wp_;
    wp_ += (bytes + 255) & ~(size_t)255;
    return p;
  };
  // zero-region (one memset): barriers | h1 | h2 | stats | att2acc | v2
  char* zbase = wp_;
  c.leafs = (int*)alloc(256 * 4);
  c.root = (int*)alloc(256);
  c.h1 = (float*)alloc((size_t)B * 512 * 4);
  c.h2 = (float*)alloc((size_t)B * 512 * 4);
  c.stats1 = (float*)alloc(2 * 64 * 2 * 4);
  c.stats2 = (float*)alloc(2 * 64 * 2 * 4);
  c.att2acc = (float*)alloc((size_t)B * 256 * 4);
  c.v2 = (float*)alloc((size_t)B * 512 * 4);
  size_t zbytes = (size_t)(wp_ - zbase);

  c.order_i = (int*)alloc(B * 4);
  c.declen = (int*)alloc(B * 4);
  c.caps_s = (int*)alloc((size_t)B * MAXLEN * 4);
  c.EaT = (float*)alloc((size_t)512 * 128 * 4);
  c.att1 = (float*)alloc((size_t)B * P * 128 * 4);
  c.v1 = (float*)alloc((size_t)B * 512 * 4);
  c.gin = (float*)alloc((size_t)B * 768 * 4);
  c.fgr = (float*)alloc((size_t)B * 1024 * 4);
  c.gh1g = (float*)alloc((size_t)B * 1536 * 4);
  c.gh2g = (float*)alloc((size_t)B * 1536 * 4);
  c.WA = (unsigned int*)alloc((size_t)32 * 32768 * 4);
  c.WB = (unsigned int*)alloc((size_t)32 * 24576 * 4);
  c.WC = (unsigned int*)alloc((size_t)32 * 12288 * 4);
  c.WD = (unsigned int*)alloc((size_t)32 * 32768 * 4);
  c.Watt = (float*)alloc((size_t)8 * 16384 * 4);
  c.Sf = (float*)alloc(1024 * 4);
  c.cbf = (float*)alloc(1024 * 4);
  c.Sg = (float*)alloc(1536 * 4);
  c.cbg = (float*)alloc(1536 * 4);

  hipMemsetAsync(d_out, 0, (size_t)out_size * 4, stream);
  hipMemsetAsync(zbase, 0, zbytes, stream);

  k_order<<<1, 64, 0, stream>>>(c);
  k_caps<<<(B * MAXLEN + 255) / 256, 256, 0, stream>>>(c);
  k_eat<<<(128 * 512 + 255) / 256, 256, 0, stream>>>(c);
  k_att1<<<(B * P) / 8, 256, 0, stream>>>(c);
  k_wpa<<<32, 256, 0, stream>>>(c);
  k_wpb<<<32, 256, 0, stream>>>(c);
  k_wpc<<<32, 256, 0, stream>>>(c);
  k_wpd<<<32, 256, 0, stream>>>(c);
  k_watt<<<8, 256, 0, stream>>>(c);
  k_consts<<<2560, 256, 0, stream>>>(c);

  persist<<<256, 512, 0, stream>>>(c);
}